// Round 2
// baseline (429.446 us; speedup 1.0000x reference)
//
#include <hip/hip_runtime.h>

#define BB 128
#define II 512
#define HH 256
#define OO 32
#define FF 16
#define OF 512

// ---------------- Kernel A: partial column-sums of x over i ----------------
// grid = B*8, block = 256 (one thread per h). Each block sums 64 rows.
__global__ __launch_bounds__(256) void k_xsum(
    const float* __restrict__ x, float* __restrict__ xsum_part) {
  int t = threadIdx.x;                 // h
  int blk = blockIdx.x;                // b*8 + chunk
  int b = blk >> 3, ch = blk & 7;
  const float* xp = x + ((size_t)b * II + (size_t)ch * 64) * HH + t;
  float a = 0.f;
#pragma unroll 8
  for (int i = 0; i < 64; ++i) a += xp[(size_t)i * HH];
  xsum_part[(size_t)blk * HH + t] = a;
}

// ---------------- Kernel B: v1 = squash((1/32) * xsum @ W) ----------------
// grid = B, block = 512 (thread t -> o = t>>4, f = t&15)
__global__ __launch_bounds__(512) void k_v1(
    const float* __restrict__ xsum_part, const float* __restrict__ W,
    float* __restrict__ v) {
  __shared__ float xs[HH];
  int t = threadIdx.x;
  int b = blockIdx.x;
  if (t < HH) {
    float a = 0.f;
#pragma unroll
    for (int ch = 0; ch < 8; ++ch) a += xsum_part[((size_t)b * 8 + ch) * HH + t];
    xs[t] = a;
  }
  __syncthreads();
  float acc = 0.f;
#pragma unroll 4
  for (int h = 0; h < HH; ++h)
    acc += xs[h] * W[(size_t)h * OF + t];
  acc *= (1.0f / 32.0f);
  // squash across the 16 f-lanes of each o-group
  float n2 = acc * acc;
#pragma unroll
  for (int mask = 1; mask < 16; mask <<= 1) n2 += __shfl_xor(n2, mask);
  float scale = sqrtf(n2) / (1.f + n2);
  v[(size_t)b * OF + t] = acc * scale;
}

// ---------------- Kernel C: Wv[b,h,o] = sum_f W[h,o*16+f] * v[b,o,f] ------
// grid = B, block = 256
__global__ __launch_bounds__(256) void k_wv(
    const float* __restrict__ W, const float* __restrict__ v,
    float* __restrict__ Wv) {
  __shared__ float vs[OF];
  int t = threadIdx.x;
  int b = blockIdx.x;
  vs[t] = v[(size_t)b * OF + t];
  vs[t + 256] = v[(size_t)b * OF + t + 256];
  __syncthreads();
  float* wvp = Wv + (size_t)b * HH * OO;
#pragma unroll 2
  for (int jj = 0; jj < 32; ++jj) {
    int idx = jj * 256 + t;
    int o = idx & 31, h = idx >> 5;
    const float* wp = W + (size_t)h * OF + o * FF;
    float acc = 0.f;
#pragma unroll
    for (int f = 0; f < FF; ++f) acc += wp[f] * vs[o * FF + f];
    wvp[(size_t)h * OO + o] = acc;
  }
}

// ---------------- Kernel D: blog[b,i,o] = sum_h x[b,i,h]*Wv[b,h,o], softmax over o
// grid = B*64 (each block: 8 i-rows), block = 256 (thread: li = t>>5, o = t&31)
__global__ __launch_bounds__(256) void k_blog(
    const float* __restrict__ x, const float* __restrict__ Wv,
    float* __restrict__ c) {
  __shared__ float xls[8 * HH];   // 8 KB
  __shared__ float wvs[HH * OO];  // 32 KB
  int t = threadIdx.x;
  int blk = blockIdx.x;
  int b = blk >> 6;
  int i0 = (blk & 63) * 8;
  const float* xp = x + ((size_t)b * II + i0) * HH;
#pragma unroll
  for (int j = 0; j < 8; ++j) xls[j * 256 + t] = xp[j * 256 + t];
  const float* wvp = Wv + (size_t)b * HH * OO;
#pragma unroll
  for (int j = 0; j < 32; ++j) wvs[j * 256 + t] = wvp[j * 256 + t];
  __syncthreads();
  int o = t & 31;
  int li = t >> 5;
  float acc = 0.f;
#pragma unroll 4
  for (int h = 0; h < HH; ++h) acc += xls[li * HH + h] * wvs[h * OO + o];
  // softmax over the 32 o-lanes (each 32-lane group = one i row)
  float m = acc;
#pragma unroll
  for (int mask = 1; mask < 32; mask <<= 1) m = fmaxf(m, __shfl_xor(m, mask));
  float e = __expf(acc - m);
  float s = e;
#pragma unroll
  for (int mask = 1; mask < 32; mask <<= 1) s += __shfl_xor(s, mask);
  c[((size_t)b * II + i0 + li) * OO + o] = e / s;
}

// ---------------- Kernel E: cx[b,o,h] = sum_i c[b,i,o] * x[b,i,h] ----------
// grid = B*8 (4 o's per block), block = 256 (thread per h)
__global__ __launch_bounds__(256) void k_cx(
    const float* __restrict__ x, const float* __restrict__ c,
    float* __restrict__ cx) {
  int t = threadIdx.x;   // h
  int blk = blockIdx.x;
  int b = blk >> 3;
  int o0 = (blk & 7) * 4;
  const float* xp = x + (size_t)b * II * HH + t;
  const float* cp = c + (size_t)b * II * OO + o0;
  float a0 = 0.f, a1 = 0.f, a2 = 0.f, a3 = 0.f;
#pragma unroll 4
  for (int i = 0; i < II; ++i) {
    float xv = xp[(size_t)i * HH];
    float c0 = cp[i * OO + 0], c1 = cp[i * OO + 1];
    float c2 = cp[i * OO + 2], c3 = cp[i * OO + 3];
    a0 += c0 * xv; a1 += c1 * xv; a2 += c2 * xv; a3 += c3 * xv;
  }
  float* cxp = cx + ((size_t)b * OO + o0) * HH + t;
  cxp[0] = a0; cxp[HH] = a1; cxp[2 * HH] = a2; cxp[3 * HH] = a3;
}

// ---------------- Kernel F: v[b,o,f] = squash(sum_h cx[b,o,h]*W[h,o*16+f]) -
// grid = B*O, block = 64 (one wave; f = lane&15, quarter q = lane>>4)
__global__ __launch_bounds__(64) void k_v(
    const float* __restrict__ cx, const float* __restrict__ W,
    float* __restrict__ v, float* __restrict__ out, int final_) {
  int lane = threadIdx.x;
  int blk = blockIdx.x;
  int o = blk & 31;
  int f = lane & 15, q = lane >> 4;
  const float* cxp = cx + (size_t)blk * HH;
  const float* wp = W + o * FF + f;
  float acc = 0.f;
#pragma unroll 4
  for (int j = 0; j < 64; ++j) {
    int h = q * 64 + j;
    acc += cxp[h] * wp[(size_t)h * OF];
  }
  // sum the 4 h-quarters (butterfly over lane bits 4,5)
  acc += __shfl_xor(acc, 16);
  acc += __shfl_xor(acc, 32);
  // squash across f
  float n2 = acc * acc;
#pragma unroll
  for (int mask = 1; mask < 16; mask <<= 1) n2 += __shfl_xor(n2, mask);
  float scale = sqrtf(n2) / (1.f + n2);
  float res = acc * scale;
  if (q == 0) {
    if (final_) out[(size_t)blk * FF + f] = res;
    else v[(size_t)blk * FF + f] = res;
  }
}

extern "C" void kernel_launch(void* const* d_in, const int* in_sizes, int n_in,
                              void* d_out, int out_size, void* d_ws, size_t ws_size,
                              hipStream_t stream) {
  const float* x = (const float*)d_in[0];  // [128,512,256] fp32
  const float* W = (const float*)d_in[1];  // [1,256,512]   fp32
  float* out = (float*)d_out;              // [128,32,16]   fp32
  float* ws = (float*)d_ws;
  // workspace layout (floats): ~17.3 MiB total
  float* xsum_part = ws;              // B*8*H   = 262144
  float* v   = ws + 262144;           // B*O*F   = 65536
  float* Wv  = ws + 327680;           // B*H*O   = 1048576
  float* c   = ws + 1376256;          // B*I*O   = 2097152
  float* cx  = ws + 3473408;          // B*O*H   = 1048576

  k_xsum<<<BB * 8, 256, 0, stream>>>(x, xsum_part);
  k_v1<<<BB, 512, 0, stream>>>(xsum_part, W, v);
  for (int it = 0; it < 2; ++it) {
    k_wv<<<BB, 256, 0, stream>>>(W, v, Wv);
    k_blog<<<BB * 64, 256, 0, stream>>>(x, Wv, c);
    k_cx<<<BB * 8, 256, 0, stream>>>(x, c, cx);
    k_v<<<BB * OO, 64, 0, stream>>>(cx, W, v, out, it == 1);
  }
}

// Round 3
// 297.252 us; speedup vs baseline: 1.4447x; 1.4447x over previous
//
#include <hip/hip_runtime.h>

#define BB 128
#define II 512
#define HH 256
#define OO 32
#define FF 16
#define OF 512
#define CI 64          // i-rows per routing block
#define NP 8           // partials per b (II/CI)
#define XPAD 260       // padded LDS row stride in floats (1040 B = 65*16, float4-aligned)

// ---------------- Kernel A: partial column-sums of x over i ----------------
__global__ __launch_bounds__(256) void k_xsum(
    const float* __restrict__ x, float* __restrict__ xsum_part) {
  int t = threadIdx.x;                 // h
  int blk = blockIdx.x;                // b*8 + chunk
  int b = blk >> 3, ch = blk & 7;
  const float* xp = x + ((size_t)b * II + (size_t)ch * 64) * HH + t;
  float a = 0.f;
#pragma unroll 8
  for (int i = 0; i < 64; ++i) a += xp[(size_t)i * HH];
  xsum_part[(size_t)blk * HH + t] = a;
}

// ---------------- Kernel B: v1 = squash((1/32) * xsum @ W) ----------------
__global__ __launch_bounds__(512) void k_v1(
    const float* __restrict__ xsum_part, const float* __restrict__ W,
    float* __restrict__ v) {
  __shared__ float xs[HH];
  int t = threadIdx.x;
  int b = blockIdx.x;
  if (t < HH) {
    float a = 0.f;
#pragma unroll
    for (int ch = 0; ch < 8; ++ch) a += xsum_part[((size_t)b * 8 + ch) * HH + t];
    xs[t] = a;
  }
  __syncthreads();
  float acc = 0.f;
#pragma unroll 4
  for (int h = 0; h < HH; ++h)
    acc += xs[h] * W[(size_t)h * OF + t];
  acc *= (1.0f / 32.0f);
  float n2 = acc * acc;
#pragma unroll
  for (int mask = 1; mask < 16; mask <<= 1) n2 += __shfl_xor(n2, mask);
  float scale = sqrtf(n2) / (1.f + n2);
  v[(size_t)b * OF + t] = acc * scale;
}

// ---------------- Kernel C: wvT[b,o,h] = sum_f W[h,o*16+f] * v[b,o,f] ------
// transposed output layout [b][o][h] so k_route can read float4 over h.
__global__ __launch_bounds__(256) void k_wv(
    const float* __restrict__ W, const float* __restrict__ v,
    float* __restrict__ wvT) {
  __shared__ float vs[OF];
  int t = threadIdx.x;
  int b = blockIdx.x;
  vs[t] = v[(size_t)b * OF + t];
  vs[t + 256] = v[(size_t)b * OF + t + 256];
  __syncthreads();
  float* wvp = wvT + (size_t)b * OO * HH;
#pragma unroll 2
  for (int jj = 0; jj < 32; ++jj) {
    int idx = jj * 256 + t;
    int h = idx & 255, o = idx >> 8;
    const float* wp = W + (size_t)h * OF + o * FF;
    float acc = 0.f;
#pragma unroll
    for (int f = 0; f < FF; ++f) acc += wp[f] * vs[o * FF + f];
    wvp[(size_t)o * HH + h] = acc;       // coalesced over h
  }
}

// ---------------- Kernel D (fused): blog -> softmax -> partial cx ----------
// grid = B*NP, block = 256, 2 blocks/CU (LDS 74.75 KB)
__global__ __launch_bounds__(256, 2) void k_route(
    const float* __restrict__ x, const float* __restrict__ wvT,
    float* __restrict__ cxp) {
  __shared__ float xls[CI * XPAD];   // 66.56 KB, padded rows
  __shared__ float cs[CI * OO];      // 8 KB
  int t = threadIdx.x;
  int blk = blockIdx.x;
  int b = blk >> 3, p = blk & 7;

  // ---- phase 1: stage x chunk [CI][HH] into padded LDS ----
  const float4* xp4 = (const float4*)(x + ((size_t)b * II + (size_t)p * CI) * HH);
#pragma unroll
  for (int jj = 0; jj < 16; ++jj) {
    int idx = jj * 256 + t;              // float4 index 0..4095
    int row = idx >> 6, col = idx & 63;  // 64 float4 per row
    *(float4*)&xls[row * XPAD + col * 4] = xp4[idx];
  }
  __syncthreads();

  // ---- phase 2: logits + softmax -> cs ----
  {
    int o = t & 31, rg = t >> 5;         // thread tile: rows rg*8..+7, one o
    const float* wp = wvT + ((size_t)b * OO + o) * HH;
    float acc[8] = {0.f, 0.f, 0.f, 0.f, 0.f, 0.f, 0.f, 0.f};
    const float* xbase = &xls[rg * 8 * XPAD];
    for (int h = 0; h < HH; h += 4) {
      float4 w4 = *(const float4*)&wp[h];
#pragma unroll
      for (int j = 0; j < 8; ++j) {
        float4 x4 = *(const float4*)&xbase[j * XPAD + h];  // half-wave broadcast
        acc[j] += x4.x * w4.x + x4.y * w4.y + x4.z * w4.z + x4.w * w4.w;
      }
    }
#pragma unroll
    for (int j = 0; j < 8; ++j) {
      float vv = acc[j];
      float m = vv;
#pragma unroll
      for (int mask = 1; mask < 32; mask <<= 1) m = fmaxf(m, __shfl_xor(m, mask));
      float e = __expf(vv - m);
      float s = e;
#pragma unroll
      for (int mask = 1; mask < 32; mask <<= 1) s += __shfl_xor(s, mask);
      cs[(rg * 8 + j) * OO + o] = e / s;   // bank = o -> conflict-free
    }
  }
  __syncthreads();

  // ---- phase 3: partial cx[o][h] = sum_i cs[i][o] * xls[i][h] ----
  {
    int hg = t & 63, og = t >> 6;        // tile: 8 o x 4 h
    int h0 = hg * 4, o0 = og * 8;
    float4 a4[8];
#pragma unroll
    for (int j = 0; j < 8; ++j) a4[j] = make_float4(0.f, 0.f, 0.f, 0.f);
    for (int i = 0; i < CI; ++i) {
      float4 x4 = *(const float4*)&xls[i * XPAD + h0];       // stride-1, no conflict
      float4 c0 = *(const float4*)&cs[i * OO + o0];          // wave-broadcast
      float4 c1 = *(const float4*)&cs[i * OO + o0 + 4];      // wave-broadcast
      float cv[8] = {c0.x, c0.y, c0.z, c0.w, c1.x, c1.y, c1.z, c1.w};
#pragma unroll
      for (int j = 0; j < 8; ++j) {
        a4[j].x += cv[j] * x4.x;
        a4[j].y += cv[j] * x4.y;
        a4[j].z += cv[j] * x4.z;
        a4[j].w += cv[j] * x4.w;
      }
    }
    float* outp = cxp + ((size_t)blk * OO + o0) * HH + h0;
#pragma unroll
    for (int j = 0; j < 8; ++j)
      *(float4*)&outp[(size_t)j * HH] = a4[j];               // coalesced
  }
}

// ---------------- Kernel E: v[b,o,f] = squash(sum_h (sum_p cxp)*W) ---------
// grid = B*O, block = 64; also performs the 8-way partial reduction inline.
__global__ __launch_bounds__(64) void k_v(
    const float* __restrict__ cxp, const float* __restrict__ W,
    float* __restrict__ v, float* __restrict__ out, int final_) {
  int lane = threadIdx.x;
  int blk = blockIdx.x;                 // b*32 + o
  int b = blk >> 5, o = blk & 31;
  int f = lane & 15, q = lane >> 4;
  const float* wp = W + o * FF + f;
  const float* cp = cxp + (((size_t)b * NP) * OO + o) * HH;
  float acc = 0.f;
#pragma unroll 4
  for (int j = 0; j < 64; ++j) {
    int h = q * 64 + j;
    float cxv = 0.f;
#pragma unroll
    for (int p = 0; p < NP; ++p)
      cxv += cp[(size_t)p * OO * HH + h];
    acc += cxv * wp[(size_t)h * OF];
  }
  acc += __shfl_xor(acc, 16);
  acc += __shfl_xor(acc, 32);
  float n2 = acc * acc;
#pragma unroll
  for (int mask = 1; mask < 16; mask <<= 1) n2 += __shfl_xor(n2, mask);
  float scale = sqrtf(n2) / (1.f + n2);
  float res = acc * scale;
  if (q == 0) {
    if (final_) out[(size_t)blk * FF + f] = res;
    else v[(size_t)blk * FF + f] = res;
  }
}

extern "C" void kernel_launch(void* const* d_in, const int* in_sizes, int n_in,
                              void* d_out, int out_size, void* d_ws, size_t ws_size,
                              hipStream_t stream) {
  const float* x = (const float*)d_in[0];  // [128,512,256] fp32
  const float* W = (const float*)d_in[1];  // [1,256,512]   fp32
  float* out = (float*)d_out;              // [128,32,16]   fp32
  float* ws = (float*)d_ws;
  // workspace (floats): total 9,764,864 = 39.1 MiB
  float* xsum_part = ws;                  // B*8*H = 262144
  float* v   = ws + 262144;               // B*O*F = 65536
  float* wvT = ws + 327680;               // B*O*H = 1048576
  float* cxp = ws + 1376256;              // B*NP*O*H = 8388608

  k_xsum<<<BB * 8, 256, 0, stream>>>(x, xsum_part);
  k_v1<<<BB, 512, 0, stream>>>(xsum_part, W, v);
  for (int it = 0; it < 2; ++it) {
    k_wv<<<BB, 256, 0, stream>>>(W, v, wvT);
    k_route<<<BB * NP, 256, 0, stream>>>(x, wvT, cxp);
    k_v<<<BB * OO, 64, 0, stream>>>(cxp, W, v, out, it == 1);
  }
}